// Round 6
// baseline (442.787 us; speedup 1.0000x reference)
//
#include <hip/hip_runtime.h>
#include <cstdint>
#include <cstddef>

#define B_ 16
#define T_ 8192
#define D_ 256
#define U_ 256

typedef __attribute__((ext_vector_type(8))) short bf16x8;
typedef __attribute__((ext_vector_type(4))) float f32x4;
typedef __attribute__((ext_vector_type(4))) unsigned int u32x4;

__device__ inline f32x4 mfma16(bf16x8 a, bf16x8 b, f32x4 c) {
    return __builtin_amdgcn_mfma_f32_16x16x32_bf16(a, b, c, 0, 0, 0);
}

// pack high-16 (truncated bf16) of two fp32 into one u32: [y_hi16 : x_hi16]
__device__ inline unsigned int pack2_hi(float x, float y) {
    return __builtin_amdgcn_perm(__float_as_uint(y), __float_as_uint(x), 0x07060302u);
}
__device__ inline float lo_part(float x) {
    return x - __uint_as_float(__float_as_uint(x) & 0xffff0000u);
}

// convert 8 fp32 (two float4s) -> bf16 hi/lo fragments (truncation split)
__device__ inline void cvt8v(const float4 a, const float4 b, bf16x8& hi, bf16x8& lo) {
    u32x4 h, l;
    h[0] = pack2_hi(a.x, a.y);
    h[1] = pack2_hi(a.z, a.w);
    h[2] = pack2_hi(b.x, b.y);
    h[3] = pack2_hi(b.z, b.w);
    l[0] = pack2_hi(lo_part(a.x), lo_part(a.y));
    l[1] = pack2_hi(lo_part(a.z), lo_part(a.w));
    l[2] = pack2_hi(lo_part(b.x), lo_part(b.y));
    l[3] = pack2_hi(lo_part(b.z), lo_part(b.w));
    hi = __builtin_bit_cast(bf16x8, h);
    lo = __builtin_bit_cast(bf16x8, l);
}

// ---------------- Kernel 0: W1 [d][u] -> W1^T bf16 hi/lo [u][d] ----------------
__global__ __launch_bounds__(256) void prep_w1t_kernel(const float* __restrict__ W1,
                                                       unsigned short* __restrict__ hi,
                                                       unsigned short* __restrict__ lo) {
    const int idx = blockIdx.x * 256 + threadIdx.x;   // 0..65535
    const int d = idx >> 8;
    const int u = idx & 255;
    const float x = W1[idx];
    const unsigned int xb = __float_as_uint(x);
    const unsigned short h = (unsigned short)(xb >> 16);
    const float lf = x - __uint_as_float(xb & 0xffff0000u);
    const unsigned short lo16 = (unsigned short)(__float_as_uint(lf) >> 16);
    hi[u * D_ + d] = h;
    lo[u * D_ + d] = lo16;
}

// ---------------- Kernel 1: hidden = query @ W2  -> [B, U] ----------------
__global__ __launch_bounds__(256) void hidden_kernel(const float* __restrict__ q,
                                                     const float* __restrict__ W2,
                                                     float* __restrict__ hidden) {
    const int b = blockIdx.x;
    const int u = threadIdx.x;
    __shared__ float qs[D_];
    qs[u] = q[b * D_ + u];
    __syncthreads();
    float acc = 0.f;
#pragma unroll 8
    for (int d = 0; d < D_; ++d)
        acc += qs[d] * W2[d * U_ + u];
    hidden[b * U_ + u] = acc;
}

// ---------------- Kernel 2: fused scores + chunk softmax + chunk context ----------
// Block: 256 threads = 4 waves, 128 t-rows x 256 u. Wave w owns rows [w*32,w*32+32) x ALL u.
// SINGLE-buffered B in LDS (33 KB total) -> 4 blocks/CU = 16 waves/CU; intra-block
// barrier stalls are covered by the 3 other resident blocks.
// Per k-step: cvt A(k) -> reload a-regs with A(k+1) -> 96 MFMA on buf -> sync ->
// stage B(k+1) into buf -> sync.
// B LDS layout: lane-ordered fragments bhi[uf][lane*8..+8] -> linear ds_read_b128,
// conflict-free; staged via global_load_lds (per-lane global src, uniform LDS base).
__global__ __launch_bounds__(256, 4) void scores_ctx_kernel(
        const float* __restrict__ value,
        const unsigned short* __restrict__ w1t_hi,
        const unsigned short* __restrict__ w1t_lo,
        const float* __restrict__ Vv,
        const float* __restrict__ hidden,
        float* __restrict__ partial,
        float* __restrict__ mstat,
        float* __restrict__ lstat) {
    const int b    = blockIdx.y;
    const int bx   = blockIdx.x;
    const int t0   = bx * 128;
    const int tid  = threadIdx.x;
    const int w    = tid >> 6;
    const int lane = tid & 63;
    const int lr   = lane & 15;
    const int lk   = lane >> 4;

    __shared__ unsigned short bhi[16 * 512];   // 16 KB
    __shared__ unsigned short blo[16 * 512];   // 16 KB
    __shared__ float s_lds[128];
    __shared__ float e_lds[128];
    __shared__ float redm[4];
    __shared__ float redl[4];

    // each wave stages 4 uf tiles (hi+lo): uf = w*4 .. w*4+3
    auto stage_b = [&](int k0) {
#pragma unroll
        for (int i = 0; i < 4; ++i) {
            const int uf = w * 4 + i;
            const unsigned short* gh = w1t_hi + (size_t)(uf * 16 + lr) * D_ + k0 + lk * 8;
            __builtin_amdgcn_global_load_lds(
                (const __attribute__((address_space(1))) void*)gh,
                (__attribute__((address_space(3))) void*)&bhi[uf * 512],
                16, 0, 0);
            const unsigned short* gl = w1t_lo + (size_t)(uf * 16 + lr) * D_ + k0 + lk * 8;
            __builtin_amdgcn_global_load_lds(
                (const __attribute__((address_space(1))) void*)gl,
                (__attribute__((address_space(3))) void*)&blo[uf * 512],
                16, 0, 0);
        }
    };

    f32x4 acc[2][16] = {};
    const float* aptr = value + ((size_t)b * T_ + t0 + w * 32 + lr) * D_ + lk * 8;

    // prologue: A(0) to regs, stage B(0)
    float4 a0[2], a1[2];
#pragma unroll
    for (int tf = 0; tf < 2; ++tf) {
        a0[tf] = *reinterpret_cast<const float4*>(aptr + (size_t)tf * 16 * D_);
        a1[tf] = *reinterpret_cast<const float4*>(aptr + (size_t)tf * 16 * D_ + 4);
    }
    stage_b(0);
    __syncthreads();

    for (int k = 0; k < 8; ++k) {
        const int k0 = k << 5;

        // consume A(k) into bf16 fragments, then immediately reload A(k+1)
        // (register WAR only; loads land during MFMA + stage phases)
        bf16x8 ah[2], al[2];
#pragma unroll
        for (int tf = 0; tf < 2; ++tf)
            cvt8v(a0[tf], a1[tf], ah[tf], al[tf]);
        if (k < 7) {
#pragma unroll
            for (int tf = 0; tf < 2; ++tf) {
                a0[tf] = *reinterpret_cast<const float4*>(aptr + (size_t)tf * 16 * D_ + k0 + 32);
                a1[tf] = *reinterpret_cast<const float4*>(aptr + (size_t)tf * 16 * D_ + k0 + 36);
            }
        }

#pragma unroll
        for (int uf = 0; uf < 16; ++uf) {
            const bf16x8 bh = *reinterpret_cast<const bf16x8*>(&bhi[uf * 512 + lane * 8]);
            const bf16x8 bl = *reinterpret_cast<const bf16x8*>(&blo[uf * 512 + lane * 8]);
#pragma unroll
            for (int tf = 0; tf < 2; ++tf) {
                acc[tf][uf] = mfma16(ah[tf], bh, acc[tf][uf]);
                acc[tf][uf] = mfma16(al[tf], bh, acc[tf][uf]);
                acc[tf][uf] = mfma16(ah[tf], bl, acc[tf][uf]);
            }
        }

        if (k < 7) {
            __syncthreads();          // all waves done reading buf
            stage_b(k0 + 32);         // overwrite with B(k+1)
            __syncthreads();          // staged (vmcnt drained by barrier)
        }
    }

    // ---- epilogue: tanh + dot V, reduce over u within wave ----
    float hv[16], vwv[16];
#pragma unroll
    for (int uf = 0; uf < 16; ++uf) {
        const int u = uf * 16 + lr;
        hv[uf]  = hidden[b * U_ + u];
        vwv[uf] = Vv[u];
    }
#pragma unroll
    for (int tf = 0; tf < 2; ++tf) {
#pragma unroll
        for (int r = 0; r < 4; ++r) {
            float p = 0.f;
#pragma unroll
            for (int uf = 0; uf < 16; ++uf) {
                const float z = acc[tf][uf][r] + hv[uf];
                const float e = __expf(2.f * z);
                p += (1.f - __fdividef(2.f, e + 1.f)) * vwv[uf];
            }
            p += __shfl_xor(p, 1, 64);
            p += __shfl_xor(p, 2, 64);
            p += __shfl_xor(p, 4, 64);
            p += __shfl_xor(p, 8, 64);
            if (lr == 0) s_lds[w * 32 + tf * 16 + lk * 4 + r] = p;
        }
    }
    __syncthreads();

    // ---- chunk softmax (max, sum) over the 128 local scores ----
    float x = (tid < 128) ? s_lds[tid] : -3e38f;
#pragma unroll
    for (int m = 1; m < 64; m <<= 1) x = fmaxf(x, __shfl_xor(x, m, 64));
    if (lane == 0) redm[w] = x;
    __syncthreads();
    const float mc = fmaxf(fmaxf(redm[0], redm[1]), fmaxf(redm[2], redm[3]));

    float e = 0.f;
    if (tid < 128) {
        e = __expf(s_lds[tid] - mc);
        e_lds[tid] = e;
    }
    float l = e;
#pragma unroll
    for (int m = 1; m < 64; m <<= 1) l += __shfl_xor(l, m, 64);
    if (lane == 0) redl[w] = l;
    __syncthreads();
    const float lc = redl[0] + redl[1] + redl[2] + redl[3];

    // ---- chunk context: ctx[d] = sum_t e_t * value[t][d]  (rows are L2/L3-hot) ----
    const float* vb = value + ((size_t)b * T_ + t0) * D_ + tid;
    float ca0 = 0.f, ca1 = 0.f;
#pragma unroll 8
    for (int t = 0; t < 128; t += 2) {
        ca0 += e_lds[t]     * vb[(size_t)t * D_];
        ca1 += e_lds[t + 1] * vb[(size_t)(t + 1) * D_];
    }
    partial[((size_t)b * 64 + bx) * D_ + tid] = ca0 + ca1;
    if (tid == 0) {
        mstat[b * 64 + bx] = mc;
        lstat[b * 64 + bx] = lc;
    }
}

// ---------------- Kernel 3: cross-chunk softmax merge ----------------
__global__ __launch_bounds__(256) void combine_kernel(const float* __restrict__ partial,
                                                      const float* __restrict__ mstat,
                                                      const float* __restrict__ lstat,
                                                      float* __restrict__ out) {
    const int b = blockIdx.x;
    const int d = threadIdx.x;
    float M = -3e38f;
#pragma unroll 8
    for (int c = 0; c < 64; ++c) M = fmaxf(M, mstat[b * 64 + c]);
    float L = 0.f, a = 0.f;
#pragma unroll 4
    for (int c = 0; c < 64; ++c) {
        const float s = __expf(mstat[b * 64 + c] - M);
        L += lstat[b * 64 + c] * s;
        a += s * partial[((size_t)b * 64 + c) * D_ + d];
    }
    out[b * D_ + d] = a / L;
}

extern "C" void kernel_launch(void* const* d_in, const int* in_sizes, int n_in,
                              void* d_out, int out_size, void* d_ws, size_t ws_size,
                              hipStream_t stream) {
    const float* q     = (const float*)d_in[0];
    const float* value = (const float*)d_in[1];
    const float* W1    = (const float*)d_in[2];
    const float* W2    = (const float*)d_in[3];
    const float* Vv    = (const float*)d_in[4];
    float* out = (float*)d_out;

    char* ws = (char*)d_ws;
    unsigned short* w1t_hi  = (unsigned short*)(ws);                  // 131072 B
    unsigned short* w1t_lo  = (unsigned short*)(ws + 131072);         // 131072 B
    float*          hidden  = (float*)(ws + 262144);                  //  16384 B
    float*          partial = (float*)(ws + 278528);                  // 1048576 B
    float*          mstat   = (float*)(ws + 1327104);                 //   4096 B
    float*          lstat   = (float*)(ws + 1331200);                 //   4096 B

    prep_w1t_kernel<<<dim3(256), dim3(256), 0, stream>>>(W1, w1t_hi, w1t_lo);
    hidden_kernel<<<dim3(B_), dim3(256), 0, stream>>>(q, W2, hidden);

    dim3 g2(T_ / 128, B_);
    scores_ctx_kernel<<<g2, dim3(256), 0, stream>>>(value, w1t_hi, w1t_lo, Vv, hidden,
                                                    partial, mstat, lstat);

    combine_kernel<<<dim3(B_), dim3(256), 0, stream>>>(partial, mstat, lstat, out);
}

// Round 7
// 106.702 us; speedup vs baseline: 4.1497x; 4.1497x over previous
//
#include <hip/hip_runtime.h>
#include <cstdint>
#include <cstddef>

#define B_ 16
#define T_ 8192
#define D_ 256
#define U_ 256

typedef __attribute__((ext_vector_type(8))) short bf16x8;
typedef __attribute__((ext_vector_type(4))) float f32x4;
typedef __attribute__((ext_vector_type(4))) unsigned int u32x4;

#define VMCNT(N) asm volatile("s_waitcnt vmcnt(" #N ")" ::: "memory")
#define SBAR()   asm volatile("s_barrier" ::: "memory")
#define FENCE()  asm volatile("" ::: "memory")

__device__ inline f32x4 mfma16(bf16x8 a, bf16x8 b, f32x4 c) {
    return __builtin_amdgcn_mfma_f32_16x16x32_bf16(a, b, c, 0, 0, 0);
}

// pack high-16 (truncated bf16) of two fp32 into one u32: [y_hi16 : x_hi16]
__device__ inline unsigned int pack2_hi(float x, float y) {
    return __builtin_amdgcn_perm(__float_as_uint(y), __float_as_uint(x), 0x07060302u);
}
__device__ inline float lo_part(float x) {
    return x - __uint_as_float(__float_as_uint(x) & 0xffff0000u);
}

// convert 8 fp32 (two float4s) -> bf16 hi/lo fragments (truncation split)
__device__ inline void cvt8v(const float4 a, const float4 b, bf16x8& hi, bf16x8& lo) {
    u32x4 h, l;
    h[0] = pack2_hi(a.x, a.y);
    h[1] = pack2_hi(a.z, a.w);
    h[2] = pack2_hi(b.x, b.y);
    h[3] = pack2_hi(b.z, b.w);
    l[0] = pack2_hi(lo_part(a.x), lo_part(a.y));
    l[1] = pack2_hi(lo_part(a.z), lo_part(a.w));
    l[2] = pack2_hi(lo_part(b.x), lo_part(b.y));
    l[3] = pack2_hi(lo_part(b.z), lo_part(b.w));
    hi = __builtin_bit_cast(bf16x8, h);
    lo = __builtin_bit_cast(bf16x8, l);
}

// ---------------- Kernel 0: W1 [d][u] -> W1^T bf16 hi/lo [u][d] ----------------
__global__ __launch_bounds__(256) void prep_w1t_kernel(const float* __restrict__ W1,
                                                       unsigned short* __restrict__ hi,
                                                       unsigned short* __restrict__ lo) {
    const int idx = blockIdx.x * 256 + threadIdx.x;   // 0..65535
    const int d = idx >> 8;
    const int u = idx & 255;
    const float x = W1[idx];
    const unsigned int xb = __float_as_uint(x);
    const unsigned short h = (unsigned short)(xb >> 16);
    const float lf = x - __uint_as_float(xb & 0xffff0000u);
    const unsigned short lo16 = (unsigned short)(__float_as_uint(lf) >> 16);
    hi[u * D_ + d] = h;
    lo[u * D_ + d] = lo16;
}

// ---------------- Kernel 1: hidden = query @ W2  -> [B, U] ----------------
__global__ __launch_bounds__(256) void hidden_kernel(const float* __restrict__ q,
                                                     const float* __restrict__ W2,
                                                     float* __restrict__ hidden) {
    const int b = blockIdx.x;
    const int u = threadIdx.x;
    __shared__ float qs[D_];
    qs[u] = q[b * D_ + u];
    __syncthreads();
    float acc = 0.f;
#pragma unroll 8
    for (int d = 0; d < D_; ++d)
        acc += qs[d] * W2[d * U_ + u];
    hidden[b * U_ + u] = acc;
}

// ---------------- Kernel 2: fused scores + chunk softmax + chunk context ----------
// Block: 256 threads = 4 waves, 128 t-rows x 256 u. Wave w owns rows [w*32,w*32+32) x ALL u.
// Per iter: issue stage(k+1)->buf[nxt] (8 gl_lds, OLDEST) then A(k+1) loads (4),
// then a memory-asm FENCE pins those issues ABOVE the MFMA cluster (loads cannot
// sink, ds_reads/MFMA cannot hoist). End of iter: s_waitcnt vmcnt(4) retires all
// stage ops (A may stay in flight) + raw s_barrier (no lgkm/vm drain).
// Steady state: zero exposed memory waits; A latency (~900cy HBM) and stage
// latency (~300cy L2) hide under the ~1900cy MFMA phase.
__global__ __launch_bounds__(256, 2) void scores_ctx_kernel(
        const float* __restrict__ value,
        const unsigned short* __restrict__ w1t_hi,
        const unsigned short* __restrict__ w1t_lo,
        const float* __restrict__ Vv,
        const float* __restrict__ hidden,
        float* __restrict__ partial,
        float* __restrict__ mstat,
        float* __restrict__ lstat) {
    const int b    = blockIdx.y;
    const int bx   = blockIdx.x;
    const int t0   = bx * 128;
    const int tid  = threadIdx.x;
    const int w    = tid >> 6;
    const int lane = tid & 63;
    const int lr   = lane & 15;
    const int lk   = lane >> 4;

    __shared__ unsigned short bhi[2][16 * 512];   // 32 KB
    __shared__ unsigned short blo[2][16 * 512];   // 32 KB
    __shared__ float s_lds[128];
    __shared__ float e_lds[128];
    __shared__ float redm[4];
    __shared__ float redl[4];

    // each wave stages 4 uf tiles (hi+lo): uf = w*4 .. w*4+3
    auto stage_b = [&](int bf, int k0) {
#pragma unroll
        for (int i = 0; i < 4; ++i) {
            const int uf = w * 4 + i;
            const unsigned short* gh = w1t_hi + (size_t)(uf * 16 + lr) * D_ + k0 + lk * 8;
            __builtin_amdgcn_global_load_lds(
                (const __attribute__((address_space(1))) void*)gh,
                (__attribute__((address_space(3))) void*)&bhi[bf][uf * 512],
                16, 0, 0);
            const unsigned short* gl = w1t_lo + (size_t)(uf * 16 + lr) * D_ + k0 + lk * 8;
            __builtin_amdgcn_global_load_lds(
                (const __attribute__((address_space(1))) void*)gl,
                (__attribute__((address_space(3))) void*)&blo[bf][uf * 512],
                16, 0, 0);
        }
    };

    f32x4 acc[2][16] = {};
    const float* aptr = value + ((size_t)b * T_ + t0 + w * 32 + lr) * D_ + lk * 8;

    // prologue: stage B(0) (oldest), then A(0) loads; stage retired via vmcnt(4)
    stage_b(0, 0);
    float4 a0[2], a1[2];
#pragma unroll
    for (int tf = 0; tf < 2; ++tf) {
        a0[tf] = *reinterpret_cast<const float4*>(aptr + (size_t)tf * 16 * D_);
        a1[tf] = *reinterpret_cast<const float4*>(aptr + (size_t)tf * 16 * D_ + 4);
    }
    FENCE();
    VMCNT(4);        // all 8 stage ops retired; A(0) may still fly
    SBAR();

    int cur = 0;
    for (int k = 0; k < 8; ++k) {
        const int k0 = k << 5;

        // issue next tile: stage FIRST (oldest), then A prefetch
        float4 n0[2], n1[2];
        if (k < 7) {
            stage_b(cur ^ 1, k0 + 32);
#pragma unroll
            for (int tf = 0; tf < 2; ++tf) {
                n0[tf] = *reinterpret_cast<const float4*>(aptr + (size_t)tf * 16 * D_ + k0 + 32);
                n1[tf] = *reinterpret_cast<const float4*>(aptr + (size_t)tf * 16 * D_ + k0 + 36);
            }
        }
        FENCE();     // pin: issues above cannot sink below; compute cannot hoist above

        bf16x8 ah[2], al[2];
#pragma unroll
        for (int tf = 0; tf < 2; ++tf)
            cvt8v(a0[tf], a1[tf], ah[tf], al[tf]);

#pragma unroll
        for (int uf = 0; uf < 16; ++uf) {
            const bf16x8 bh = *reinterpret_cast<const bf16x8*>(&bhi[cur][uf * 512 + lane * 8]);
            const bf16x8 bl = *reinterpret_cast<const bf16x8*>(&blo[cur][uf * 512 + lane * 8]);
#pragma unroll
            for (int tf = 0; tf < 2; ++tf) {
                acc[tf][uf] = mfma16(ah[tf], bh, acc[tf][uf]);
                acc[tf][uf] = mfma16(al[tf], bh, acc[tf][uf]);
                acc[tf][uf] = mfma16(ah[tf], bl, acc[tf][uf]);
            }
        }

        if (k < 7) {
            VMCNT(4);    // own stage(k+1) retired; A(k+1) may fly (compiler waits at cvt)
            SBAR();      // all waves staged nxt & finished reading cur; no drain
#pragma unroll
            for (int tf = 0; tf < 2; ++tf) { a0[tf] = n0[tf]; a1[tf] = n1[tf]; }
        }
        cur ^= 1;
    }

    // ---- epilogue: tanh + dot V, reduce over u within wave ----
    float hv[16], vwv[16];
#pragma unroll
    for (int uf = 0; uf < 16; ++uf) {
        const int u = uf * 16 + lr;
        hv[uf]  = hidden[b * U_ + u];
        vwv[uf] = Vv[u];
    }
#pragma unroll
    for (int tf = 0; tf < 2; ++tf) {
#pragma unroll
        for (int r = 0; r < 4; ++r) {
            float p = 0.f;
#pragma unroll
            for (int uf = 0; uf < 16; ++uf) {
                const float z = acc[tf][uf][r] + hv[uf];
                const float e = __expf(2.f * z);
                p += (1.f - __fdividef(2.f, e + 1.f)) * vwv[uf];
            }
            p += __shfl_xor(p, 1, 64);
            p += __shfl_xor(p, 2, 64);
            p += __shfl_xor(p, 4, 64);
            p += __shfl_xor(p, 8, 64);
            if (lr == 0) s_lds[w * 32 + tf * 16 + lk * 4 + r] = p;
        }
    }
    __syncthreads();

    // ---- chunk softmax (max, sum) over the 128 local scores ----
    float x = (tid < 128) ? s_lds[tid] : -3e38f;
#pragma unroll
    for (int m = 1; m < 64; m <<= 1) x = fmaxf(x, __shfl_xor(x, m, 64));
    if (lane == 0) redm[w] = x;
    __syncthreads();
    const float mc = fmaxf(fmaxf(redm[0], redm[1]), fmaxf(redm[2], redm[3]));

    float e = 0.f;
    if (tid < 128) {
        e = __expf(s_lds[tid] - mc);
        e_lds[tid] = e;
    }
    float l = e;
#pragma unroll
    for (int m = 1; m < 64; m <<= 1) l += __shfl_xor(l, m, 64);
    if (lane == 0) redl[w] = l;
    __syncthreads();
    const float lc = redl[0] + redl[1] + redl[2] + redl[3];

    // ---- chunk context: ctx[d] = sum_t e_t * value[t][d]  (rows are L2/L3-hot) ----
    const float* vb = value + ((size_t)b * T_ + t0) * D_ + tid;
    float ca0 = 0.f, ca1 = 0.f;
#pragma unroll 8
    for (int t = 0; t < 128; t += 2) {
        ca0 += e_lds[t]     * vb[(size_t)t * D_];
        ca1 += e_lds[t + 1] * vb[(size_t)(t + 1) * D_];
    }
    partial[((size_t)b * 64 + bx) * D_ + tid] = ca0 + ca1;
    if (tid == 0) {
        mstat[b * 64 + bx] = mc;
        lstat[b * 64 + bx] = lc;
    }
}

// ---------------- Kernel 3: cross-chunk softmax merge ----------------
__global__ __launch_bounds__(256) void combine_kernel(const float* __restrict__ partial,
                                                      const float* __restrict__ mstat,
                                                      const float* __restrict__ lstat,
                                                      float* __restrict__ out) {
    const int b = blockIdx.x;
    const int d = threadIdx.x;
    float M = -3e38f;
#pragma unroll 8
    for (int c = 0; c < 64; ++c) M = fmaxf(M, mstat[b * 64 + c]);
    float L = 0.f, a = 0.f;
#pragma unroll 4
    for (int c = 0; c < 64; ++c) {
        const float s = __expf(mstat[b * 64 + c] - M);
        L += lstat[b * 64 + c] * s;
        a += s * partial[((size_t)b * 64 + c) * D_ + d];
    }
    out[b * D_ + d] = a / L;
}

extern "C" void kernel_launch(void* const* d_in, const int* in_sizes, int n_in,
                              void* d_out, int out_size, void* d_ws, size_t ws_size,
                              hipStream_t stream) {
    const float* q     = (const float*)d_in[0];
    const float* value = (const float*)d_in[1];
    const float* W1    = (const float*)d_in[2];
    const float* W2    = (const float*)d_in[3];
    const float* Vv    = (const float*)d_in[4];
    float* out = (float*)d_out;

    char* ws = (char*)d_ws;
    unsigned short* w1t_hi  = (unsigned short*)(ws);                  // 131072 B
    unsigned short* w1t_lo  = (unsigned short*)(ws + 131072);         // 131072 B
    float*          hidden  = (float*)(ws + 262144);                  //  16384 B
    float*          partial = (float*)(ws + 278528);                  // 1048576 B
    float*          mstat   = (float*)(ws + 1327104);                 //   4096 B
    float*          lstat   = (float*)(ws + 1331200);                 //   4096 B

    prep_w1t_kernel<<<dim3(256), dim3(256), 0, stream>>>(W1, w1t_hi, w1t_lo);
    hidden_kernel<<<dim3(B_), dim3(256), 0, stream>>>(q, W2, hidden);

    dim3 g2(T_ / 128, B_);
    scores_ctx_kernel<<<g2, dim3(256), 0, stream>>>(value, w1t_hi, w1t_lo, Vv, hidden,
                                                    partial, mstat, lstat);

    combine_kernel<<<dim3(B_), dim3(256), 0, stream>>>(partial, mstat, lstat, out);
}